// Round 7
// baseline (121.917 us; speedup 1.0000x reference)
//
#include <hip/hip_runtime.h>
#include <hip/hip_bf16.h>

#define B_DIM 4
#define C_DIM 256
#define N_DIM 4096
#define NBLK  128   // N_DIM / 32

typedef unsigned short ushort8 __attribute__((ext_vector_type(8)));
typedef short          short8  __attribute__((ext_vector_type(8)));
typedef float          f32x4   __attribute__((ext_vector_type(4)));

__device__ __forceinline__ unsigned short f2bf(float x) {
    __hip_bfloat16 h = __float2bfloat16(x);
    return __builtin_bit_cast(unsigned short, h);
}
__device__ __forceinline__ float b2f(unsigned short u) {
    return __builtin_bit_cast(float, (unsigned)u << 16);
}
__device__ __forceinline__ unsigned pack2(float a, float b) {
    return (unsigned)f2bf(a) | ((unsigned)f2bf(b) << 16);
}

// ---------------------------------------------------------------------------
// castXW: one launch does both precasts (R1-proven).
//  z = 0..3 : X fp32 [b][c][n] -> XT bf16 [b][n][c]  (64x64 LDS transpose)
//  z = 4    : W fp32 [r][c] -> bf16 [r][c]; 1/sqrt(256) folded into Wk.
// ---------------------------------------------------------------------------
__global__ __launch_bounds__(256) void castXW(
    const float* __restrict__ X, unsigned short* __restrict__ XT,
    const float* __restrict__ Wk, const float* __restrict__ Wv,
    unsigned short* __restrict__ Wkb, unsigned short* __restrict__ Wvb)
{
    __shared__ float tile[64][65];
    const int tid = threadIdx.x;
    const int b = blockIdx.z;

    if (b == 4) {                       // ---- W cast slice ----
        const int bid = blockIdx.y * 64 + blockIdx.x;
        if (bid >= 64) return;
        const int mat = bid >> 5;       // 0: Wk, 1: Wv
        const float* src = mat ? Wv : Wk;
        unsigned short* dst = mat ? Wvb : Wkb;
        const float scale = mat ? 1.0f : 0.0625f;
        int idx = (bid & 31) * 2048 + tid * 8;
        float4 f0 = *(const float4*)(src + idx);
        float4 f1 = *(const float4*)(src + idx + 4);
        ushort8 u;
        u[0] = f2bf(f0.x * scale); u[1] = f2bf(f0.y * scale);
        u[2] = f2bf(f0.z * scale); u[3] = f2bf(f0.w * scale);
        u[4] = f2bf(f1.x * scale); u[5] = f2bf(f1.y * scale);
        u[6] = f2bf(f1.z * scale); u[7] = f2bf(f1.w * scale);
        *(ushort8*)(dst + idx) = u;
        return;
    }

    // ---- X transpose-cast slice ----
    const int n0 = blockIdx.x * 64, c0 = blockIdx.y * 64;
    {
        int c = tid >> 2, ns = (tid & 3) * 16;
        const float* src = X + ((size_t)(b * C_DIM + c0 + c)) * N_DIM + n0 + ns;
        #pragma unroll
        for (int j = 0; j < 4; ++j) {
            float4 f = *(const float4*)(src + j * 4);
            tile[c][ns + j * 4 + 0] = f.x; tile[c][ns + j * 4 + 1] = f.y;
            tile[c][ns + j * 4 + 2] = f.z; tile[c][ns + j * 4 + 3] = f.w;
        }
    }
    __syncthreads();
    {
        int n = tid >> 2, cs = (tid & 3) * 16;
        ushort8 u0, u1;
        #pragma unroll
        for (int j = 0; j < 8; ++j) u0[j] = f2bf(tile[cs + j][n]);
        #pragma unroll
        for (int j = 0; j < 8; ++j) u1[j] = f2bf(tile[cs + 8 + j][n]);
        unsigned short* dst = XT + ((size_t)b * N_DIM + n0 + n) * C_DIM + c0 + cs;
        *(ushort8*)dst       = u0;
        *(ushort8*)(dst + 8) = u1;
    }
}

// ---------------------------------------------------------------------------
// kvs v3: wave-specialized fused K+V GEMM + scores.  Grid (N/32, B), 512 thr.
//  waves 0..3 (K-waves): K = Wk·x for 48 cols -> Kl bf16; then OWN the full
//    scores chain: each thread covers 2 r-chunks (no fold), reduce, exp,
//    denominators, EWT emit.
//  waves 4..7 (V-waves): V = Wv·x for 32 cols -> global bf16; then AFTER the
//    sw barrier compute colsum partials Sp[b][blk][c] straight from their
//    still-live accumulator registers (4x shfl_xor per value).  Their store
//    latency and Sp work overlap the K-waves' scores instead of lock-stepping.
//  H tile staged to LDS bf16 (sink-proof) by all threads before B2.
// ---------------------------------------------------------------------------
__global__ __launch_bounds__(512) void kvs(
    const unsigned short* __restrict__ XT,
    const unsigned short* __restrict__ Wkb,
    const unsigned short* __restrict__ Wvb,
    const float* __restrict__ H,
    unsigned short* __restrict__ Vout,
    float* __restrict__ EWT,
    float* __restrict__ Sp)
{
    __shared__ __align__(16) unsigned short Kl[36][264];   // k cols n0-2..n0+33
    __shared__ __align__(16) unsigned short Hst[32][264];  // h cols n0..n0+31
    __shared__ float sacc[8][5][32];
    __shared__ float se[5][32];
    __shared__ float sw[32];

    const int b   = blockIdx.y;
    const int n0  = blockIdx.x * 32;
    const int tid = threadIdx.x;
    const int lane = tid & 63, wid = tid >> 6;
    const int ln = lane & 15, q = lane >> 4;
    const int nl = tid & 31;

    // ---- H tile loads (issued early; consumed by LDS staging pre-barrier) --
    const int hr = tid >> 1, hh = tid & 1;           // row 0..255, 16-col half
    const float* hsrc = H + ((size_t)(b * C_DIM + hr)) * N_DIM + n0 + hh * 16;
    float4 h0 = *(const float4*)(hsrc);
    float4 h1 = *(const float4*)(hsrc + 4);
    float4 h2 = *(const float4*)(hsrc + 8);
    float4 h3 = *(const float4*)(hsrc + 12);

    const unsigned short* XTb = XT + (size_t)b * N_DIM * C_DIM;

    f32x4 acc[4][3] = {};                            // K: [4][3]; V: [4][0..1]

    if (wid < 4) {
        // ---------------- K GEMM: 64 r x 48 n per wave ----------------
        const int rbase = wid * 64;
        const unsigned short* pa0 = Wkb + (size_t)(rbase + ln) * C_DIM + q * 8;
        const unsigned short* pa1 = pa0 + 16 * C_DIM;
        const unsigned short* pa2 = pa0 + 32 * C_DIM;
        const unsigned short* pa3 = pa0 + 48 * C_DIM;
        int nn0 = n0 - 8 + ln;            // j=0 halo: clamp low edge
        nn0 = nn0 < 0 ? 0 : nn0;
        int nn1 = n0 + 8 + ln;            // j=1: always in range
        int nn2 = n0 + 24 + ln;           // j=2 halo: clamp high edge
        nn2 = nn2 > N_DIM - 1 ? N_DIM - 1 : nn2;
        const unsigned short* pb0 = XTb + (size_t)nn0 * C_DIM + q * 8;
        const unsigned short* pb1 = XTb + (size_t)nn1 * C_DIM + q * 8;
        const unsigned short* pb2 = XTb + (size_t)nn2 * C_DIM + q * 8;

        #pragma unroll
        for (int c0 = 0; c0 < C_DIM; c0 += 32) {
            short8 A0 = *(const short8*)(pa0 + c0);
            short8 A1 = *(const short8*)(pa1 + c0);
            short8 A2 = *(const short8*)(pa2 + c0);
            short8 A3 = *(const short8*)(pa3 + c0);
            short8 B0 = *(const short8*)(pb0 + c0);
            short8 B1 = *(const short8*)(pb1 + c0);
            short8 B2 = *(const short8*)(pb2 + c0);
            acc[0][0] = __builtin_amdgcn_mfma_f32_16x16x32_bf16(A0, B0, acc[0][0], 0, 0, 0);
            acc[1][0] = __builtin_amdgcn_mfma_f32_16x16x32_bf16(A1, B0, acc[1][0], 0, 0, 0);
            acc[2][0] = __builtin_amdgcn_mfma_f32_16x16x32_bf16(A2, B0, acc[2][0], 0, 0, 0);
            acc[3][0] = __builtin_amdgcn_mfma_f32_16x16x32_bf16(A3, B0, acc[3][0], 0, 0, 0);
            acc[0][1] = __builtin_amdgcn_mfma_f32_16x16x32_bf16(A0, B1, acc[0][1], 0, 0, 0);
            acc[1][1] = __builtin_amdgcn_mfma_f32_16x16x32_bf16(A1, B1, acc[1][1], 0, 0, 0);
            acc[2][1] = __builtin_amdgcn_mfma_f32_16x16x32_bf16(A2, B1, acc[2][1], 0, 0, 0);
            acc[3][1] = __builtin_amdgcn_mfma_f32_16x16x32_bf16(A3, B1, acc[3][1], 0, 0, 0);
            acc[0][2] = __builtin_amdgcn_mfma_f32_16x16x32_bf16(A0, B2, acc[0][2], 0, 0, 0);
            acc[1][2] = __builtin_amdgcn_mfma_f32_16x16x32_bf16(A1, B2, acc[1][2], 0, 0, 0);
            acc[2][2] = __builtin_amdgcn_mfma_f32_16x16x32_bf16(A2, B2, acc[2][2], 0, 0, 0);
            acc[3][2] = __builtin_amdgcn_mfma_f32_16x16x32_bf16(A3, B2, acc[3][2], 0, 0, 0);
        }
        // K -> Kl bf16, keep local rows 6..41 (= k cols n0-2 .. n0+33)
        #pragma unroll
        for (int j = 0; j < 3; ++j) {
            const int rowk = j * 16 + ln;
            if (rowk >= 6 && rowk < 42) {
                const int rb = wid * 64;
                #pragma unroll
                for (int i = 0; i < 4; ++i) {
                    unsigned* p = (unsigned*)&Kl[rowk - 6][rb + i * 16 + q * 4];
                    p[0] = pack2(acc[i][j][0], acc[i][j][1]);
                    p[1] = pack2(acc[i][j][2], acc[i][j][3]);
                }
            }
        }
    } else {
        // ---------------- V GEMM: 64 c x 32 n per wave ----------------
        const int cbase = (wid - 4) * 64;
        const unsigned short* pa0 = Wvb + (size_t)(cbase + ln) * C_DIM + q * 8;
        const unsigned short* pa1 = pa0 + 16 * C_DIM;
        const unsigned short* pa2 = pa0 + 32 * C_DIM;
        const unsigned short* pa3 = pa0 + 48 * C_DIM;
        const unsigned short* pb0 = XTb + (size_t)(n0 + ln) * C_DIM + q * 8;
        const unsigned short* pb1 = pb0 + 16 * C_DIM;

        #pragma unroll
        for (int c0 = 0; c0 < C_DIM; c0 += 32) {
            short8 A0 = *(const short8*)(pa0 + c0);
            short8 A1 = *(const short8*)(pa1 + c0);
            short8 A2 = *(const short8*)(pa2 + c0);
            short8 A3 = *(const short8*)(pa3 + c0);
            short8 B0 = *(const short8*)(pb0 + c0);
            short8 B1 = *(const short8*)(pb1 + c0);
            acc[0][0] = __builtin_amdgcn_mfma_f32_16x16x32_bf16(A0, B0, acc[0][0], 0, 0, 0);
            acc[1][0] = __builtin_amdgcn_mfma_f32_16x16x32_bf16(A1, B0, acc[1][0], 0, 0, 0);
            acc[2][0] = __builtin_amdgcn_mfma_f32_16x16x32_bf16(A2, B0, acc[2][0], 0, 0, 0);
            acc[3][0] = __builtin_amdgcn_mfma_f32_16x16x32_bf16(A3, B0, acc[3][0], 0, 0, 0);
            acc[0][1] = __builtin_amdgcn_mfma_f32_16x16x32_bf16(A0, B1, acc[0][1], 0, 0, 0);
            acc[1][1] = __builtin_amdgcn_mfma_f32_16x16x32_bf16(A1, B1, acc[1][1], 0, 0, 0);
            acc[2][1] = __builtin_amdgcn_mfma_f32_16x16x32_bf16(A2, B1, acc[2][1], 0, 0, 0);
            acc[3][1] = __builtin_amdgcn_mfma_f32_16x16x32_bf16(A3, B1, acc[3][1], 0, 0, 0);
        }
        unsigned short* Vb = Vout + (size_t)b * C_DIM * N_DIM;
        #pragma unroll
        for (int i = 0; i < 4; ++i)
            #pragma unroll
            for (int reg = 0; reg < 4; ++reg) {
                int r = cbase + i * 16 + q * 4 + reg;
                size_t base = (size_t)r * N_DIM + n0 + ln;
                Vb[base]      = f2bf(acc[i][0][reg]);
                Vb[base + 16] = f2bf(acc[i][1][reg]);
            }
        // acc[i][0..1] stays live for the Sp partial after B5.
    }

    // ---- H -> Hst LDS (bf16, transposed); ds_writes can't sink past B2 ----
    {
        const int cb = hh * 16;
        Hst[cb + 0][hr] = f2bf(h0.x); Hst[cb + 1][hr] = f2bf(h0.y);
        Hst[cb + 2][hr] = f2bf(h0.z); Hst[cb + 3][hr] = f2bf(h0.w);
        Hst[cb + 4][hr] = f2bf(h1.x); Hst[cb + 5][hr] = f2bf(h1.y);
        Hst[cb + 6][hr] = f2bf(h1.z); Hst[cb + 7][hr] = f2bf(h1.w);
        Hst[cb + 8][hr] = f2bf(h2.x); Hst[cb + 9][hr] = f2bf(h2.y);
        Hst[cb +10][hr] = f2bf(h2.z); Hst[cb +11][hr] = f2bf(h2.w);
        Hst[cb +12][hr] = f2bf(h3.x); Hst[cb +13][hr] = f2bf(h3.y);
        Hst[cb +14][hr] = f2bf(h3.z); Hst[cb +15][hr] = f2bf(h3.w);
    }
    __syncthreads();   // B2: Kl + Hst ready

    // ---- scores (K-waves only): each thread covers r-chunks {sch, sch+8} --
    if (wid < 4) {
        const int sch = tid >> 5;                    // 0..7
        float hf[32];
        {
            const short8 hA = *(const short8*)&Hst[nl][sch * 16];
            const short8 hB = *(const short8*)&Hst[nl][sch * 16 + 8];
            const short8 hC = *(const short8*)&Hst[nl][(sch + 8) * 16];
            const short8 hD = *(const short8*)&Hst[nl][(sch + 8) * 16 + 8];
            #pragma unroll
            for (int t = 0; t < 8; ++t) {
                hf[t]      = b2f((unsigned short)hA[t]);
                hf[t + 8]  = b2f((unsigned short)hB[t]);
                hf[t + 16] = b2f((unsigned short)hC[t]);
                hf[t + 24] = b2f((unsigned short)hD[t]);
            }
        }
        #pragma unroll
        for (int dd = 0; dd < 5; ++dd) {
            const short8 k0 = *(const short8*)&Kl[nl + dd][sch * 16];
            const short8 k1 = *(const short8*)&Kl[nl + dd][sch * 16 + 8];
            const short8 k2 = *(const short8*)&Kl[nl + dd][(sch + 8) * 16];
            const short8 k3 = *(const short8*)&Kl[nl + dd][(sch + 8) * 16 + 8];
            float s = 0.f;
            #pragma unroll
            for (int t = 0; t < 8; ++t) {
                s = fmaf(hf[t],      b2f((unsigned short)k0[t]), s);
                s = fmaf(hf[t + 8],  b2f((unsigned short)k1[t]), s);
                s = fmaf(hf[t + 16], b2f((unsigned short)k2[t]), s);
                s = fmaf(hf[t + 24], b2f((unsigned short)k3[t]), s);
            }
            sacc[sch][dd][nl] = s;
        }
    }
    __syncthreads();   // B3

    // ---- reduce 8 chunk-slots + exp (K-wave threads) ----
    if (tid < 160) {
        const int dd = tid >> 5, nn = tid & 31;
        float s = 0.f;
        #pragma unroll
        for (int c2 = 0; c2 < 8; ++c2) s += sacc[c2][dd][nn];
        const int mm = n0 + nn + dd - 2;             // attended column
        se[dd][nn] = (mm >= 0 && mm < N_DIM) ? expf(s) - 1.0f : 0.f;
    }
    __syncthreads();   // B4

    // ---- denominators + EWT emit ----
    if (tid < 32) {
        float ear[5];
        #pragma unroll
        for (int dd = 0; dd < 5; ++dd) ear[dd] = se[dd][tid];
        const float w = 1.0f / ((float)N_DIM + ear[0] + ear[1] + ear[2]
                                             + ear[3] + ear[4]);
        sw[tid] = w;
        #pragma unroll
        for (int dd = 0; dd < 5; ++dd) {
            const int mm = n0 + tid + dd - 2;        // output column
            if (mm >= 0 && mm < N_DIM)
                EWT[((size_t)b * 5 + (4 - dd)) * N_DIM + mm] = ear[dd] * w;
        }
    }
    // zero the 6 never-written EWT edge slots (insurance vs ws poison)
    if (blockIdx.x == 0 && tid >= 64 && tid < 70) {
        const size_t base = (size_t)b * 5 * N_DIM;
        const int t = tid - 64;
        if (t == 0) EWT[base + 0 * N_DIM + 0] = 0.f;
        if (t == 1) EWT[base + 0 * N_DIM + 1] = 0.f;
        if (t == 2) EWT[base + 1 * N_DIM + 0] = 0.f;
        if (t == 3) EWT[base + 3 * N_DIM + (N_DIM - 1)] = 0.f;
        if (t == 4) EWT[base + 4 * N_DIM + (N_DIM - 2)] = 0.f;
        if (t == 5) EWT[base + 4 * N_DIM + (N_DIM - 1)] = 0.f;
    }
    __syncthreads();   // B5: sw ready for V-waves

    // ---- V-waves: colsum partials Sp[b][blk][c] from live acc regs ----
    if (wid >= 4) {
        const int cbase = (wid - 4) * 64;
        const float s0 = sw[ln], s1 = sw[ln + 16];
        #pragma unroll
        for (int i = 0; i < 4; ++i)
            #pragma unroll
            for (int reg = 0; reg < 4; ++reg) {
                float v = acc[i][0][reg] * s0 + acc[i][1][reg] * s1;
                v += __shfl_xor(v, 1, 64);
                v += __shfl_xor(v, 2, 64);
                v += __shfl_xor(v, 4, 64);
                v += __shfl_xor(v, 8, 64);
                if (ln == 0)
                    Sp[((size_t)b * NBLK + blockIdx.x) * C_DIM
                       + cbase + i * 16 + q * 4 + reg] = v;
            }
    }
}

// ---------------------------------------------------------------------------
// epi v2: band epilogue + Sp reduce.  One block per (b,c) row.
//  S = sum_blk Sp[b][blk][c]  (precomputed partials; no V re-reduction), then
//  out[m] = x[m] + S + sum_{dd=0..4} v[m+dd-2] * EWT[b][dd][m]
// ---------------------------------------------------------------------------
__global__ __launch_bounds__(256) void epi(
    const float* __restrict__ X,
    const unsigned short* __restrict__ V,
    const float* __restrict__ EWT,
    const float* __restrict__ Sp,
    float* __restrict__ Out)
{
    __shared__ unsigned short sv[N_DIM + 8];   // [0..3]=0, v at +4, tail 0
    __shared__ float sd[128];
    __shared__ float sredS;

    const int c = blockIdx.x, b = blockIdx.y;
    const int tid = threadIdx.x;
    const size_t row = (size_t)b * C_DIM + c;

    if (tid < 4) { sv[tid] = 0; sv[N_DIM + 4 + tid] = 0; }
    if (tid < 128) sd[tid] = Sp[((size_t)b * NBLK + tid) * C_DIM + c];

    const ushort8* v8 = (const ushort8*)(V + row * N_DIM);
    #pragma unroll
    for (int it = 0; it < 2; ++it) {
        int i = tid + it * 256;                 // chunk of 8
        ushort8 u = v8[i];
        *(unsigned*)&sv[4 + i * 8]     = (unsigned)u[0] | ((unsigned)u[1] << 16);
        *(unsigned*)&sv[4 + i * 8 + 2] = (unsigned)u[2] | ((unsigned)u[3] << 16);
        *(unsigned*)&sv[4 + i * 8 + 4] = (unsigned)u[4] | ((unsigned)u[5] << 16);
        *(unsigned*)&sv[4 + i * 8 + 6] = (unsigned)u[6] | ((unsigned)u[7] << 16);
    }
    __syncthreads();
    if (tid < 64) {
        float v = sd[tid] + sd[tid + 64];
        #pragma unroll
        for (int off = 32; off > 0; off >>= 1)
            v += __shfl_down(v, off, 64);
        if (tid == 0) sredS = v;
    }
    __syncthreads();
    const float S = sredS;

    const float* xrow = X + row * N_DIM;
    float*       orow = Out + row * N_DIM;
    const float* ewt  = EWT + (size_t)b * 5 * N_DIM;
    const unsigned int* svw = (const unsigned int*)sv;

    #pragma unroll
    for (int it = 0; it < 4; ++it) {
        const int g  = it * 256 + tid;          // float4 index
        const int m0 = g * 4;
        const float4 x = *(const float4*)(xrow + m0);
        unsigned int u0 = svw[2 * g + 1];
        unsigned int u1 = svw[2 * g + 2];
        unsigned int u2 = svw[2 * g + 3];
        unsigned int u3 = svw[2 * g + 4];
        float w8[8];
        w8[0] = b2f(u0 & 0xffff); w8[1] = b2f(u0 >> 16);
        w8[2] = b2f(u1 & 0xffff); w8[3] = b2f(u1 >> 16);
        w8[4] = b2f(u2 & 0xffff); w8[5] = b2f(u2 >> 16);
        w8[6] = b2f(u3 & 0xffff); w8[7] = b2f(u3 >> 16);
        const float4 t0 = *(const float4*)(ewt + 0 * N_DIM + m0);
        const float4 t1 = *(const float4*)(ewt + 1 * N_DIM + m0);
        const float4 t2 = *(const float4*)(ewt + 2 * N_DIM + m0);
        const float4 t3 = *(const float4*)(ewt + 3 * N_DIM + m0);
        const float4 t4 = *(const float4*)(ewt + 4 * N_DIM + m0);
        float4 r;
        r.x = x.x + S + w8[0]*t0.x + w8[1]*t1.x + w8[2]*t2.x + w8[3]*t3.x + w8[4]*t4.x;
        r.y = x.y + S + w8[1]*t0.y + w8[2]*t1.y + w8[3]*t2.y + w8[4]*t3.y + w8[5]*t4.y;
        r.z = x.z + S + w8[2]*t0.z + w8[3]*t1.z + w8[4]*t2.z + w8[5]*t3.z + w8[6]*t4.z;
        r.w = x.w + S + w8[3]*t0.w + w8[4]*t1.w + w8[5]*t2.w + w8[6]*t3.w + w8[7]*t4.w;
        *(float4*)(orow + m0) = r;
    }
}

// ---------------------------------------------------------------------------
extern "C" void kernel_launch(void* const* d_in, const int* in_sizes, int n_in,
                              void* d_out, int out_size, void* d_ws, size_t ws_size,
                              hipStream_t stream)
{
    const float* X  = (const float*)d_in[0];   // [B,C,N]
    const float* H  = (const float*)d_in[1];   // [B,R,N]
    const float* Wk = (const float*)d_in[2];   // [R,C]
    const float* Wv = (const float*)d_in[3];   // [C,C]
    float* out = (float*)d_out;

    const size_t TENS = (size_t)B_DIM * C_DIM * N_DIM;   // 4194304
    unsigned short* XT  = (unsigned short*)d_ws;         // bf16 [b][n][c]
    unsigned short* Wkb = XT  + TENS;                    // 65536
    unsigned short* Wvb = Wkb + 65536;
    unsigned short* Vb  = Wvb + 65536;                   // bf16 [b][c][n]
    float* EWT = (float*)(Vb + TENS);                    // [b][5][m]
    float* Sp  = EWT + (size_t)B_DIM * 5 * N_DIM;        // [b][blk][c]

    castXW<<<dim3(N_DIM / 64, C_DIM / 64, B_DIM + 1), 256, 0, stream>>>(
        X, XT, Wk, Wv, Wkb, Wvb);
    kvs<<<dim3(NBLK, B_DIM), 512, 0, stream>>>(
        XT, Wkb, Wvb, H, Vb, EWT, Sp);
    epi<<<dim3(C_DIM, B_DIM), 256, 0, stream>>>(X, Vb, EWT, Sp, out);
}

// Round 8
// 118.245 us; speedup vs baseline: 1.0311x; 1.0311x over previous
//
#include <hip/hip_runtime.h>
#include <hip/hip_bf16.h>

#define B_DIM 4
#define C_DIM 256
#define N_DIM 4096
#define NBLK  128   // N_DIM / 32

typedef unsigned short ushort8 __attribute__((ext_vector_type(8)));
typedef unsigned short ushort4v __attribute__((ext_vector_type(4)));
typedef short          short8  __attribute__((ext_vector_type(8)));
typedef float          f32x4   __attribute__((ext_vector_type(4)));

__device__ __forceinline__ unsigned short f2bf(float x) {
    __hip_bfloat16 h = __float2bfloat16(x);
    return __builtin_bit_cast(unsigned short, h);
}
__device__ __forceinline__ float b2f(unsigned short u) {
    return __builtin_bit_cast(float, (unsigned)u << 16);
}

// ---------------------------------------------------------------------------
// castXW: one launch does both precasts (R1-proven).
//  z = 0..3 : X fp32 [b][c][n] -> XT bf16 [b][n][c]  (64x64 LDS transpose)
//  z = 4    : W fp32 [r][c] -> bf16 [r][c]; 1/sqrt(256) folded into Wk.
// ---------------------------------------------------------------------------
__global__ __launch_bounds__(256) void castXW(
    const float* __restrict__ X, unsigned short* __restrict__ XT,
    const float* __restrict__ Wk, const float* __restrict__ Wv,
    unsigned short* __restrict__ Wkb, unsigned short* __restrict__ Wvb)
{
    __shared__ float tile[64][65];
    const int tid = threadIdx.x;
    const int b = blockIdx.z;

    if (b == 4) {                       // ---- W cast slice ----
        const int bid = blockIdx.y * 64 + blockIdx.x;
        if (bid >= 64) return;
        const int mat = bid >> 5;       // 0: Wk, 1: Wv
        const float* src = mat ? Wv : Wk;
        unsigned short* dst = mat ? Wvb : Wkb;
        const float scale = mat ? 1.0f : 0.0625f;
        int idx = (bid & 31) * 2048 + tid * 8;
        float4 f0 = *(const float4*)(src + idx);
        float4 f1 = *(const float4*)(src + idx + 4);
        ushort8 u;
        u[0] = f2bf(f0.x * scale); u[1] = f2bf(f0.y * scale);
        u[2] = f2bf(f0.z * scale); u[3] = f2bf(f0.w * scale);
        u[4] = f2bf(f1.x * scale); u[5] = f2bf(f1.y * scale);
        u[6] = f2bf(f1.z * scale); u[7] = f2bf(f1.w * scale);
        *(ushort8*)(dst + idx) = u;
        return;
    }

    // ---- X transpose-cast slice ----
    const int n0 = blockIdx.x * 64, c0 = blockIdx.y * 64;
    {
        int c = tid >> 2, ns = (tid & 3) * 16;
        const float* src = X + ((size_t)(b * C_DIM + c0 + c)) * N_DIM + n0 + ns;
        #pragma unroll
        for (int j = 0; j < 4; ++j) {
            float4 f = *(const float4*)(src + j * 4);
            tile[c][ns + j * 4 + 0] = f.x; tile[c][ns + j * 4 + 1] = f.y;
            tile[c][ns + j * 4 + 2] = f.z; tile[c][ns + j * 4 + 3] = f.w;
        }
    }
    __syncthreads();
    {
        int n = tid >> 2, cs = (tid & 3) * 16;
        ushort8 u0, u1;
        #pragma unroll
        for (int j = 0; j < 8; ++j) u0[j] = f2bf(tile[cs + j][n]);
        #pragma unroll
        for (int j = 0; j < 8; ++j) u1[j] = f2bf(tile[cs + 8 + j][n]);
        unsigned short* dst = XT + ((size_t)b * N_DIM + n0 + n) * C_DIM + c0 + cs;
        *(ushort8*)dst       = u0;
        *(ushort8*)(dst + 8) = u1;
    }
}

// ---------------------------------------------------------------------------
// kvs (R1 structure + sink-proof H staging): fused k+v GEMM + scores.
// Grid (N/32, B), 512 thr = 8 waves.
//  Waves 0..3: K = Wk·x for 48 cols [n0-8, n0+40) x full r=256 -> K_lds (f32).
//  Waves 4..7: V = Wv·x for 32 cols [n0, n0+32) -> global bf16 (epi input).
//  All threads: load the H tile (f32) and stage to Hst LDS (bf16, transposed)
//  BEFORE the barrier -- ds_writes cannot be sunk past __syncthreads, so the
//  scores loop is guaranteed pure-LDS (this was the R1 kernel's hidden stall:
//  its register "prefetch" was sunk to the use site, re-loading H from HBM
//  inside the scores loop).
//  scores: s[n,dd] = sum_r H[r,n] K[r,n+dd-2]; 16 ch x 32 n; reduce; exp;
//  denominators; EWT/Wn emit.  LDS ~77.8 KB -> 2 blocks/CU (same as R1).
// ---------------------------------------------------------------------------
__global__ __launch_bounds__(512) void kvs(
    const unsigned short* __restrict__ XT,
    const unsigned short* __restrict__ Wkb,
    const unsigned short* __restrict__ Wvb,
    const float* __restrict__ H,
    unsigned short* __restrict__ Vout,
    float* __restrict__ EWT,
    float* __restrict__ Wout)
{
    __shared__ __align__(16) float K_lds[48][260];         // [nloc][r], ~50 KB
    __shared__ __align__(16) unsigned short Hst[32][264];  // [nloc][r] bf16
    __shared__ float sacc[16][5][32];
    __shared__ float se[5][32];
    __shared__ float sw[32];

    const int b   = blockIdx.y;
    const int n0  = blockIdx.x * 32;
    const int tid = threadIdx.x;
    const int lane = tid & 63, wid = tid >> 6;
    const int ln = lane & 15, q = lane >> 4;
    const int nl  = tid & 31;
    const int ch  = tid >> 5;          // 0..15 (r-chunk for scores)

    // ---- H tile loads: issued at the top so their latency hides under the
    //      GEMM; consumed by the LDS staging just before the barrier. ----
    const int hr = tid >> 1, hh = tid & 1;           // row 0..255, 16-col half
    const float* hsrc = H + ((size_t)(b * C_DIM + hr)) * N_DIM + n0 + hh * 16;
    float4 h0 = *(const float4*)(hsrc);
    float4 h1 = *(const float4*)(hsrc + 4);
    float4 h2 = *(const float4*)(hsrc + 8);
    float4 h3 = *(const float4*)(hsrc + 12);

    const unsigned short* XTb = XT + (size_t)b * N_DIM * C_DIM;

    if (wid < 4) {
        // ---------------- K GEMM: 64 r x 48 n per wave ----------------
        const int rbase = wid * 64;
        const unsigned short* pa0 = Wkb + (size_t)(rbase + ln) * C_DIM + q * 8;
        const unsigned short* pa1 = pa0 + 16 * C_DIM;
        const unsigned short* pa2 = pa0 + 32 * C_DIM;
        const unsigned short* pa3 = pa0 + 48 * C_DIM;
        int nn0 = n0 - 8 + ln;            // j=0 halo: clamp low edge
        nn0 = nn0 < 0 ? 0 : nn0;
        int nn1 = n0 + 8 + ln;            // j=1: always in range
        int nn2 = n0 + 24 + ln;           // j=2 halo: clamp high edge
        nn2 = nn2 > N_DIM - 1 ? N_DIM - 1 : nn2;
        const unsigned short* pb0 = XTb + (size_t)nn0 * C_DIM + q * 8;
        const unsigned short* pb1 = XTb + (size_t)nn1 * C_DIM + q * 8;
        const unsigned short* pb2 = XTb + (size_t)nn2 * C_DIM + q * 8;

        f32x4 acc[4][3] = {};
        #pragma unroll
        for (int c0 = 0; c0 < C_DIM; c0 += 32) {
            short8 A0 = *(const short8*)(pa0 + c0);
            short8 A1 = *(const short8*)(pa1 + c0);
            short8 A2 = *(const short8*)(pa2 + c0);
            short8 A3 = *(const short8*)(pa3 + c0);
            short8 B0 = *(const short8*)(pb0 + c0);
            short8 B1 = *(const short8*)(pb1 + c0);
            short8 B2 = *(const short8*)(pb2 + c0);
            acc[0][0] = __builtin_amdgcn_mfma_f32_16x16x32_bf16(A0, B0, acc[0][0], 0, 0, 0);
            acc[1][0] = __builtin_amdgcn_mfma_f32_16x16x32_bf16(A1, B0, acc[1][0], 0, 0, 0);
            acc[2][0] = __builtin_amdgcn_mfma_f32_16x16x32_bf16(A2, B0, acc[2][0], 0, 0, 0);
            acc[3][0] = __builtin_amdgcn_mfma_f32_16x16x32_bf16(A3, B0, acc[3][0], 0, 0, 0);
            acc[0][1] = __builtin_amdgcn_mfma_f32_16x16x32_bf16(A0, B1, acc[0][1], 0, 0, 0);
            acc[1][1] = __builtin_amdgcn_mfma_f32_16x16x32_bf16(A1, B1, acc[1][1], 0, 0, 0);
            acc[2][1] = __builtin_amdgcn_mfma_f32_16x16x32_bf16(A2, B1, acc[2][1], 0, 0, 0);
            acc[3][1] = __builtin_amdgcn_mfma_f32_16x16x32_bf16(A3, B1, acc[3][1], 0, 0, 0);
            acc[0][2] = __builtin_amdgcn_mfma_f32_16x16x32_bf16(A0, B2, acc[0][2], 0, 0, 0);
            acc[1][2] = __builtin_amdgcn_mfma_f32_16x16x32_bf16(A1, B2, acc[1][2], 0, 0, 0);
            acc[2][2] = __builtin_amdgcn_mfma_f32_16x16x32_bf16(A2, B2, acc[2][2], 0, 0, 0);
            acc[3][2] = __builtin_amdgcn_mfma_f32_16x16x32_bf16(A3, B2, acc[3][2], 0, 0, 0);
        }
        // K_lds write: f32x4 along r (reg dim), bank-floor pattern.
        #pragma unroll
        for (int j = 0; j < 3; ++j)
            #pragma unroll
            for (int i = 0; i < 4; ++i)
                *(f32x4*)&K_lds[j * 16 + ln][rbase + i * 16 + q * 4] = acc[i][j];
    } else {
        // ---------------- V GEMM: 64 c x 32 n per wave ----------------
        const int cbase = (wid - 4) * 64;
        const unsigned short* pa0 = Wvb + (size_t)(cbase + ln) * C_DIM + q * 8;
        const unsigned short* pa1 = pa0 + 16 * C_DIM;
        const unsigned short* pa2 = pa0 + 32 * C_DIM;
        const unsigned short* pa3 = pa0 + 48 * C_DIM;
        const unsigned short* pb0 = XTb + (size_t)(n0 + ln) * C_DIM + q * 8;
        const unsigned short* pb1 = pb0 + 16 * C_DIM;

        f32x4 acc[4][2] = {};
        #pragma unroll
        for (int c0 = 0; c0 < C_DIM; c0 += 32) {
            short8 A0 = *(const short8*)(pa0 + c0);
            short8 A1 = *(const short8*)(pa1 + c0);
            short8 A2 = *(const short8*)(pa2 + c0);
            short8 A3 = *(const short8*)(pa3 + c0);
            short8 B0 = *(const short8*)(pb0 + c0);
            short8 B1 = *(const short8*)(pb1 + c0);
            acc[0][0] = __builtin_amdgcn_mfma_f32_16x16x32_bf16(A0, B0, acc[0][0], 0, 0, 0);
            acc[1][0] = __builtin_amdgcn_mfma_f32_16x16x32_bf16(A1, B0, acc[1][0], 0, 0, 0);
            acc[2][0] = __builtin_amdgcn_mfma_f32_16x16x32_bf16(A2, B0, acc[2][0], 0, 0, 0);
            acc[3][0] = __builtin_amdgcn_mfma_f32_16x16x32_bf16(A3, B0, acc[3][0], 0, 0, 0);
            acc[0][1] = __builtin_amdgcn_mfma_f32_16x16x32_bf16(A0, B1, acc[0][1], 0, 0, 0);
            acc[1][1] = __builtin_amdgcn_mfma_f32_16x16x32_bf16(A1, B1, acc[1][1], 0, 0, 0);
            acc[2][1] = __builtin_amdgcn_mfma_f32_16x16x32_bf16(A2, B1, acc[2][1], 0, 0, 0);
            acc[3][1] = __builtin_amdgcn_mfma_f32_16x16x32_bf16(A3, B1, acc[3][1], 0, 0, 0);
        }
        unsigned short* Vb = Vout + (size_t)b * C_DIM * N_DIM;
        #pragma unroll
        for (int i = 0; i < 4; ++i)
            #pragma unroll
            for (int reg = 0; reg < 4; ++reg) {
                int r = cbase + i * 16 + q * 4 + reg;
                size_t base = (size_t)r * N_DIM + n0 + ln;
                Vb[base]      = f2bf(acc[i][0][reg]);
                Vb[base + 16] = f2bf(acc[i][1][reg]);
            }
    }

    // ---- H -> Hst LDS (bf16, transposed); ds_writes can't sink past B ----
    {
        const int cb = hh * 16;
        Hst[cb + 0][hr] = f2bf(h0.x); Hst[cb + 1][hr] = f2bf(h0.y);
        Hst[cb + 2][hr] = f2bf(h0.z); Hst[cb + 3][hr] = f2bf(h0.w);
        Hst[cb + 4][hr] = f2bf(h1.x); Hst[cb + 5][hr] = f2bf(h1.y);
        Hst[cb + 6][hr] = f2bf(h1.z); Hst[cb + 7][hr] = f2bf(h1.w);
        Hst[cb + 8][hr] = f2bf(h2.x); Hst[cb + 9][hr] = f2bf(h2.y);
        Hst[cb +10][hr] = f2bf(h2.z); Hst[cb +11][hr] = f2bf(h2.w);
        Hst[cb +12][hr] = f2bf(h3.x); Hst[cb +13][hr] = f2bf(h3.y);
        Hst[cb +14][hr] = f2bf(h3.z); Hst[cb +15][hr] = f2bf(h3.w);
    }
    __syncthreads();   // B: K_lds + Hst ready

    // ---- scores: s[n,dd] = sum_r H[r,n] * K[r,n+dd-2]; all-LDS ----
    {
        float hf[16];
        {
            const short8 hA = *(const short8*)&Hst[nl][ch * 16];
            const short8 hB = *(const short8*)&Hst[nl][ch * 16 + 8];
            #pragma unroll
            for (int t = 0; t < 8; ++t) {
                hf[t]     = b2f((unsigned short)hA[t]);
                hf[t + 8] = b2f((unsigned short)hB[t]);
            }
        }
        #pragma unroll
        for (int dd = 0; dd < 5; ++dd) {
            const f32x4* kp = (const f32x4*)&K_lds[nl + 6 + dd][ch << 4];
            f32x4 k0 = kp[0], k1 = kp[1], k2 = kp[2], k3 = kp[3];
            float s = 0.f;
            #pragma unroll
            for (int t = 0; t < 4; ++t) {
                s = fmaf(hf[t],      k0[t], s);
                s = fmaf(hf[t + 4],  k1[t], s);
                s = fmaf(hf[t + 8],  k2[t], s);
                s = fmaf(hf[t + 12], k3[t], s);
            }
            sacc[ch][dd][nl] = s;
        }
    }
    __syncthreads();

    if (tid < 160) {
        const int dd = tid >> 5, nn = tid & 31;
        float s = 0.f;
        #pragma unroll
        for (int c = 0; c < 16; ++c) s += sacc[c][dd][nn];
        const int mm = n0 + nn + dd - 2;
        se[dd][nn] = (mm >= 0 && mm < N_DIM) ? expf(s) - 1.0f : 0.f;
    }
    __syncthreads();
    if (tid < 32) {
        float denom = (float)N_DIM + se[0][tid] + se[1][tid] + se[2][tid]
                                   + se[3][tid] + se[4][tid];
        float wv = 1.0f / denom;
        sw[tid] = wv;
        Wout[(size_t)b * N_DIM + n0 + tid] = wv;
    }
    __syncthreads();
    if (tid < 160) {
        const int dd = tid >> 5, nn = tid & 31;
        const int mm = n0 + nn + dd - 2;                 // output column
        if (mm >= 0 && mm < N_DIM)
            EWT[((size_t)b * 5 + (4 - dd)) * N_DIM + mm] = se[dd][nn] * sw[nn];
    }
    // zero the 6 never-written EWT edge slots (insurance vs ws poison)
    if (blockIdx.x == 0 && tid >= 64 && tid < 70) {
        const size_t base = (size_t)b * 5 * N_DIM;
        const int t = tid - 64;
        if (t == 0) EWT[base + 0 * N_DIM + 0] = 0.f;
        if (t == 1) EWT[base + 0 * N_DIM + 1] = 0.f;
        if (t == 2) EWT[base + 1 * N_DIM + 0] = 0.f;
        if (t == 3) EWT[base + 3 * N_DIM + (N_DIM - 1)] = 0.f;
        if (t == 4) EWT[base + 4 * N_DIM + (N_DIM - 2)] = 0.f;
        if (t == 5) EWT[base + 4 * N_DIM + (N_DIM - 1)] = 0.f;
    }
}

// ---------------------------------------------------------------------------
// epi: fused colsum + epilogue, fully vectorized (R1-proven, unchanged).
//  S = sum_n v[n]*w[n]  (v staged into zero-padded LDS while reducing), then
//  out[m] = x[m] + S + sum_{dd=0..4} v[m+dd-2] * EWT[b][dd][m]
// ---------------------------------------------------------------------------
__global__ __launch_bounds__(256) void epi(
    const float* __restrict__ X,
    const unsigned short* __restrict__ V,
    const float* __restrict__ EWT,
    const float* __restrict__ Wn,
    float* __restrict__ Out)
{
    __shared__ unsigned short sv[N_DIM + 8];   // [0..3]=0, v at +4, tail 0
    __shared__ float sred[4];

    const int c = blockIdx.x, b = blockIdx.y;
    const int tid = threadIdx.x, lane = tid & 63, wid = tid >> 6;
    const size_t row = (size_t)b * C_DIM + c;

    if (tid < 4) { sv[tid] = 0; sv[N_DIM + 4 + tid] = 0; }

    const ushort8* v8   = (const ushort8*)(V + row * N_DIM);
    const float*   wrow = Wn + (size_t)b * N_DIM;

    float acc = 0.f;
    #pragma unroll
    for (int it = 0; it < 2; ++it) {
        int i = tid + it * 256;                 // chunk of 8
        ushort8 u = v8[i];
        *(ushort4v*)&sv[4 + i * 8]     = ushort4v{u[0], u[1], u[2], u[3]};
        *(ushort4v*)&sv[4 + i * 8 + 4] = ushort4v{u[4], u[5], u[6], u[7]};
        const float4 w0 = *(const float4*)(wrow + i * 8);
        const float4 w1 = *(const float4*)(wrow + i * 8 + 4);
        acc += b2f(u[0]) * w0.x + b2f(u[1]) * w0.y
             + b2f(u[2]) * w0.z + b2f(u[3]) * w0.w
             + b2f(u[4]) * w1.x + b2f(u[5]) * w1.y
             + b2f(u[6]) * w1.z + b2f(u[7]) * w1.w;
    }
    #pragma unroll
    for (int off = 32; off > 0; off >>= 1)
        acc += __shfl_down(acc, off, 64);
    if (lane == 0) sred[wid] = acc;
    __syncthreads();
    const float S = sred[0] + sred[1] + sred[2] + sred[3];

    const float* xrow = X + row * N_DIM;
    float*       orow = Out + row * N_DIM;
    const float* ewt  = EWT + (size_t)b * 5 * N_DIM;
    const unsigned int* svw = (const unsigned int*)sv;

    #pragma unroll
    for (int it = 0; it < 4; ++it) {
        const int g  = it * 256 + tid;          // float4 index
        const int m0 = g * 4;
        const float4 x = *(const float4*)(xrow + m0);
        unsigned int u0 = svw[2 * g + 1];
        unsigned int u1 = svw[2 * g + 2];
        unsigned int u2 = svw[2 * g + 3];
        unsigned int u3 = svw[2 * g + 4];
        float w8[8];
        w8[0] = b2f(u0 & 0xffff); w8[1] = b2f(u0 >> 16);
        w8[2] = b2f(u1 & 0xffff); w8[3] = b2f(u1 >> 16);
        w8[4] = b2f(u2 & 0xffff); w8[5] = b2f(u2 >> 16);
        w8[6] = b2f(u3 & 0xffff); w8[7] = b2f(u3 >> 16);
        const float4 t0 = *(const float4*)(ewt + 0 * N_DIM + m0);
        const float4 t1 = *(const float4*)(ewt + 1 * N_DIM + m0);
        const float4 t2 = *(const float4*)(ewt + 2 * N_DIM + m0);
        const float4 t3 = *(const float4*)(ewt + 3 * N_DIM + m0);
        const float4 t4 = *(const float4*)(ewt + 4 * N_DIM + m0);
        float4 r;
        r.x = x.x + S + w8[0]*t0.x + w8[1]*t1.x + w8[2]*t2.x + w8[3]*t3.x + w8[4]*t4.x;
        r.y = x.y + S + w8[1]*t0.y + w8[2]*t1.y + w8[3]*t2.y + w8[4]*t3.y + w8[5]*t4.y;
        r.z = x.z + S + w8[2]*t0.z + w8[3]*t1.z + w8[4]*t2.z + w8[5]*t3.z + w8[6]*t4.z;
        r.w = x.w + S + w8[3]*t0.w + w8[4]*t1.w + w8[5]*t2.w + w8[6]*t3.w + w8[7]*t4.w;
        *(float4*)(orow + m0) = r;
    }
}

// ---------------------------------------------------------------------------
extern "C" void kernel_launch(void* const* d_in, const int* in_sizes, int n_in,
                              void* d_out, int out_size, void* d_ws, size_t ws_size,
                              hipStream_t stream)
{
    const float* X  = (const float*)d_in[0];   // [B,C,N]
    const float* H  = (const float*)d_in[1];   // [B,R,N]
    const float* Wk = (const float*)d_in[2];   // [R,C]
    const float* Wv = (const float*)d_in[3];   // [C,C]
    float* out = (float*)d_out;

    const size_t TENS = (size_t)B_DIM * C_DIM * N_DIM;   // 4194304
    unsigned short* XT  = (unsigned short*)d_ws;         // bf16 [b][n][c]
    unsigned short* Wkb = XT  + TENS;                    // 65536
    unsigned short* Wvb = Wkb + 65536;
    unsigned short* Vb  = Wvb + 65536;                   // bf16 [b][c][n]
    float* EWT = (float*)(Vb + TENS);                    // [b][5][m]
    float* Wn  = EWT + (size_t)B_DIM * 5 * N_DIM;        // [b][n]

    castXW<<<dim3(N_DIM / 64, C_DIM / 64, B_DIM + 1), 256, 0, stream>>>(
        X, XT, Wk, Wv, Wkb, Wvb);
    kvs<<<dim3(NBLK, B_DIM), 512, 0, stream>>>(
        XT, Wkb, Wvb, H, Vb, EWT, Wn);
    epi<<<dim3(C_DIM, B_DIM), 256, 0, stream>>>(X, Vb, EWT, Wn, out);
}